// Round 3
// baseline (320.501 us; speedup 1.0000x reference)
//
#include <hip/hip_runtime.h>
#include <hip/hip_bf16.h>
#include <stdint.h>

#define NE 40000
#define FD 768
#define ED 256
#define NB 32
#define OUTC (NE + 1)

typedef __bf16 bf16x8 __attribute__((ext_vector_type(8)));
typedef float f32x4 __attribute__((ext_vector_type(4)));
typedef unsigned short ushortx8 __attribute__((ext_vector_type(8)));

// ws layout: [0,32K) qs fp32[32][256] ; [32K,96K) n01_raw fp32[64][256] ;
//            [96K,480K) Wb bf16[256][768]
#define WS_QS 0
#define WS_N01 (32 * 1024)
#define WS_WB (96 * 1024)

__device__ __forceinline__ unsigned short f2bf(float x) {
    union { float f; unsigned u; } v; v.f = x;
    unsigned r = v.u + 0x7fffu + ((v.u >> 16) & 1u);  // RNE
    return (unsigned short)(r >> 16);
}

// ---------------------------------------------------------------------------
// K0: proj_W fp32 -> bf16 (256x768).
// ---------------------------------------------------------------------------
__global__ __launch_bounds__(256) void wcvt_kernel(
    const float* __restrict__ W, unsigned short* __restrict__ Wb)
{
    int i = (blockIdx.x * 256 + threadIdx.x) * 4;
    float4 v = *(const float4*)(W + i);
    ushort4 o;
    o.x = f2bf(v.x); o.y = f2bf(v.y); o.z = f2bf(v.z); o.w = f2bf(v.w);
    *(ushort4*)(Wb + i) = o;
}

// ---------------------------------------------------------------------------
// K1a: raw projection of entity slots. 256 blocks = 64 slots x 4 dim-groups.
// Thread (dim, part p=t&3): partial dot over k = p + 4*j (float4 units) ->
// coalesced 64 B W reads per lane-quad; quad shfl-reduce.
// ---------------------------------------------------------------------------
__global__ __launch_bounds__(256) void qproj_kernel(
    const float* __restrict__ ent_pkl, const float* __restrict__ W,
    const int* __restrict__ ids, const int* __restrict__ mpos,
    float* __restrict__ n01_raw)
{
    __shared__ float row[FD];
    const int bid = blockIdx.x;
    const int t = threadIdx.x;
    const int slot = bid >> 2;          // 0..63 = b*2+s
    const int dg = bid & 3;
    const int b = slot >> 1, s = slot & 1;
    const int mp = mpos[0];
    const int col = (s < mp) ? s : s + 1;
    const bool wide = (ids[1] == 0 && ids[3] == 0 && ids[5] == 0);
    const int flat = b * 3 + col;
    const int idx = wide ? ids[flat * 2] : ids[flat];
    if (!(idx >= 1 && idx <= NE)) return;  // non-entity slots handled in K1b

    const float* src = ent_pkl + (size_t)(idx - 1) * FD;
    for (int k = t; k < FD; k += 256) row[k] = src[k];
    __syncthreads();

    const int dim = dg * 64 + (t >> 2);
    const int p = t & 3;
    const float4* w4 = (const float4*)(W + (size_t)dim * FD);
    const float4* r4 = (const float4*)row;
    float acc = 0.f;
#pragma unroll 6
    for (int j = 0; j < 48; ++j) {
        const int k4 = p + j * 4;
        float4 a = w4[k4];
        float4 r = r4[k4];
        acc += a.x * r.x + a.y * r.y + a.z * r.z + a.w * r.w;
    }
    acc += __shfl_down(acc, 2);
    acc += __shfl_down(acc, 1);
    if (p == 0) n01_raw[slot * ED + dim] = acc;
}

// ---------------------------------------------------------------------------
// K1b: per-slot normalize, qs = sum of 2 normalized slot rows, score col 0.
// ---------------------------------------------------------------------------
__global__ __launch_bounds__(256) void qsum_kernel(
    const float* __restrict__ other_emb, const float* __restrict__ n01_raw,
    const int* __restrict__ ids, const int* __restrict__ mpos,
    float* __restrict__ qs, float* __restrict__ out)
{
    __shared__ float red[4];
    __shared__ float nshare;
    const int b = blockIdx.x, t = threadIdx.x;
    const int mp = mpos[0];
    const bool wide = (ids[1] == 0 && ids[3] == 0 && ids[5] == 0);

    float q = 0.f;
#pragma unroll
    for (int s = 0; s < 2; ++s) {
        const int col = (s < mp) ? s : s + 1;
        const int flat = b * 3 + col;
        const int idx = wide ? ids[flat * 2] : ids[flat];
        float v;
        if (idx >= 1 && idx <= NE) v = n01_raw[(b * 2 + s) * ED + t];
        else if (idx == 0) v = other_emb[t];
        else v = other_emb[(size_t)(idx - NE) * ED + t];

        float ss = v * v;
#pragma unroll
        for (int o = 32; o > 0; o >>= 1) ss += __shfl_down(ss, o, 64);
        if ((t & 63) == 0) red[t >> 6] = ss;
        __syncthreads();
        if (t == 0) nshare = fmaxf(sqrtf(red[0] + red[1] + red[2] + red[3]), 1e-12f);
        __syncthreads();
        q += v / nshare;
        __syncthreads();  // protect red/nshare for next slot
    }
    qs[b * ED + t] = q;

    float d = fabsf(q - other_emb[t]);
#pragma unroll
    for (int o = 32; o > 0; o >>= 1) d += __shfl_down(d, o, 64);
    if ((t & 63) == 0) red[t >> 6] = d;
    __syncthreads();
    if (t == 0) out[(size_t)b * OUTC] = -(red[0] + red[1] + red[2] + red[3]);
}

// ---------------------------------------------------------------------------
// K2: 32 entity rows x 256 dims per block, 1250 blocks, 256 thr (4 waves,
// wave w owns cols w*64..+63). A (32x768 bf16, XOR-swizzled octets) staged
// ONCE in 48 KB LDS; B frags loaded global->VGPR from L2-hot Wb. The K-loop
// has NO barriers -> compiler pipelines loads across chunks. Scoring overlays
// the dead A region as S[32][257].
// ---------------------------------------------------------------------------
__global__ __launch_bounds__(256, 3) void gemm_score_kernel(
    const float* __restrict__ ent_pkl, const unsigned short* __restrict__ Wb,
    const float* __restrict__ qs, float* __restrict__ out)
{
    __shared__ __align__(16) unsigned short Asm[32 * FD];  // 48 KB
    float* S = (float*)Asm;                                // [32][257] overlay

    const int t = threadIdx.x;
    const int l = t & 63;
    const int w = t >> 6;       // wave -> col strip w*64
    const int ln15 = l & 15;
    const int lq = l >> 4;      // 0..3
    const int e0 = blockIdx.x * 32;

    // ---- stage A[32][768] fp32 -> bf16 into LDS, octet-swizzled ----
    {
        const int arow = t >> 3;                 // 0..31
        const int sw = arow & 7;
        const float* ap = ent_pkl + (size_t)(e0 + arow) * FD + (t & 7) * 96;
        unsigned short* aw = Asm + arow * FD;
        const int obase = (t & 7) * 12;
#pragma unroll
        for (int j = 0; j < 12; ++j) {
            float4 x = *(const float4*)(ap + j * 8);
            float4 y = *(const float4*)(ap + j * 8 + 4);
            ushortx8 v;
            v[0] = f2bf(x.x); v[1] = f2bf(x.y); v[2] = f2bf(x.z); v[3] = f2bf(x.w);
            v[4] = f2bf(y.x); v[5] = f2bf(y.y); v[6] = f2bf(y.z); v[7] = f2bf(y.w);
            *(ushortx8*)(aw + ((obase + j) ^ sw) * 8) = v;
        }
    }
    __syncthreads();

    f32x4 acc[2][4];
#pragma unroll
    for (int s = 0; s < 2; ++s)
#pragma unroll
        for (int c = 0; c < 4; ++c) acc[s][c] = (f32x4){0.f, 0.f, 0.f, 0.f};

    const unsigned short* bbase = Wb + (size_t)(w * 64 + ln15) * FD;
    const int asw = ln15 & 7;   // same swizzle for rows ln15 and 16+ln15
    const unsigned short* a0base = Asm + ln15 * FD;
    const unsigned short* a1base = Asm + (16 + ln15) * FD;

#pragma unroll 3
    for (int c = 0; c < 24; ++c) {
        const unsigned short* bp = bbase + c * 32 + lq * 8;
        bf16x8 b0 = *(const bf16x8*)(bp);
        bf16x8 b1 = *(const bf16x8*)(bp + 16 * FD);
        bf16x8 b2 = *(const bf16x8*)(bp + 32 * FD);
        bf16x8 b3 = *(const bf16x8*)(bp + 48 * FD);
        const int oct = (c * 4 + lq) ^ asw;
        bf16x8 a0 = *(const bf16x8*)(a0base + oct * 8);
        bf16x8 a1 = *(const bf16x8*)(a1base + oct * 8);
        acc[0][0] = __builtin_amdgcn_mfma_f32_16x16x32_bf16(a0, b0, acc[0][0], 0, 0, 0);
        acc[0][1] = __builtin_amdgcn_mfma_f32_16x16x32_bf16(a0, b1, acc[0][1], 0, 0, 0);
        acc[0][2] = __builtin_amdgcn_mfma_f32_16x16x32_bf16(a0, b2, acc[0][2], 0, 0, 0);
        acc[0][3] = __builtin_amdgcn_mfma_f32_16x16x32_bf16(a0, b3, acc[0][3], 0, 0, 0);
        acc[1][0] = __builtin_amdgcn_mfma_f32_16x16x32_bf16(a1, b0, acc[1][0], 0, 0, 0);
        acc[1][1] = __builtin_amdgcn_mfma_f32_16x16x32_bf16(a1, b1, acc[1][1], 0, 0, 0);
        acc[1][2] = __builtin_amdgcn_mfma_f32_16x16x32_bf16(a1, b2, acc[1][2], 0, 0, 0);
        acc[1][3] = __builtin_amdgcn_mfma_f32_16x16x32_bf16(a1, b3, acc[1][3], 0, 0, 0);
    }

    // ---- scoring: dump acc -> S[32][257], then 32 batches x 32 entities ----
    __syncthreads();  // all waves done reading Asm
#pragma unroll
    for (int s = 0; s < 2; ++s)
#pragma unroll
        for (int c = 0; c < 4; ++c)
#pragma unroll
            for (int r = 0; r < 4; ++r)
                S[(s * 16 + lq * 4 + r) * 257 + w * 64 + c * 16 + ln15] = acc[s][c][r];
    __syncthreads();

    const int sb = t & 31;      // batch
    const int eg = t >> 5;      // entity group (4 entities)
    const float* qrow = qs + sb * ED;
    const float* e0p = S + (eg * 4 + 0) * 257;
    const float* e1p = S + (eg * 4 + 1) * 257;
    const float* e2p = S + (eg * 4 + 2) * 257;
    const float* e3p = S + (eg * 4 + 3) * 257;
    float s0 = 0.f, s1 = 0.f, s2 = 0.f, s3 = 0.f;
#pragma unroll 4
    for (int d = 0; d < ED; d += 4) {
        float4 q = *(const float4*)(qrow + d);
        float4 x0 = *(const float4*)(e0p + d);
        float4 x1 = *(const float4*)(e1p + d);
        float4 x2 = *(const float4*)(e2p + d);
        float4 x3 = *(const float4*)(e3p + d);
        s0 += fabsf(q.x - x0.x) + fabsf(q.y - x0.y) + fabsf(q.z - x0.z) + fabsf(q.w - x0.w);
        s1 += fabsf(q.x - x1.x) + fabsf(q.y - x1.y) + fabsf(q.z - x1.z) + fabsf(q.w - x1.w);
        s2 += fabsf(q.x - x2.x) + fabsf(q.y - x2.y) + fabsf(q.z - x2.z) + fabsf(q.w - x2.w);
        s3 += fabsf(q.x - x3.x) + fabsf(q.y - x3.y) + fabsf(q.z - x3.z) + fabsf(q.w - x3.w);
    }
    float* op = out + (size_t)sb * OUTC + 1 + e0 + eg * 4;
    op[0] = -s0;
    op[1] = -s1;
    op[2] = -s2;
    op[3] = -s3;
}

extern "C" void kernel_launch(void* const* d_in, const int* in_sizes, int n_in,
                              void* d_out, int out_size, void* d_ws, size_t ws_size,
                              hipStream_t stream) {
    const float* ent_pkl = (const float*)d_in[0];
    const float* other_emb = (const float*)d_in[1];
    const float* proj_W = (const float*)d_in[2];
    const int* ids = (const int*)d_in[3];
    const int* mpos = (const int*)d_in[4];
    float* out = (float*)d_out;

    float* qs = (float*)((char*)d_ws + WS_QS);
    float* n01_raw = (float*)((char*)d_ws + WS_N01);
    unsigned short* Wb = (unsigned short*)((char*)d_ws + WS_WB);

    wcvt_kernel<<<(ED * FD) / 1024, 256, 0, stream>>>(proj_W, Wb);
    qproj_kernel<<<64 * 4, 256, 0, stream>>>(ent_pkl, proj_W, ids, mpos, n01_raw);
    qsum_kernel<<<NB, 256, 0, stream>>>(other_emb, n01_raw, ids, mpos, qs, out);
    gemm_score_kernel<<<NE / 32, 256, 0, stream>>>(ent_pkl, Wb, qs, out);
}